// Round 3
// baseline (192.559 us; speedup 1.0000x reference)
//
#include <hip/hip_runtime.h>
#include <math.h>

// Problem constants: B=4, L=4096, D_MODEL=1024, N_HEADS=16, D_HEAD=64, MODES=32
// Rank-64 reassociation (only 32 complex modes survive truncation):
//   A  = F @ q          [4][64][1024]  (F: 64x4096 DFT rows; split-K over t, fp32 partials)
//   C  = A @ Wv^T       (+ mode-0 bias: C[0] += 4096*bv, since sum_t cos(2pi k t/L)=0 for k!=0)
//   Y  = C * (wr + i wi)   interleaved re/im rows
//   Z  = Y @ Wo^T
//   out= G @ Z + bo     (G: 4096x64 inverse-DFT cols with 1/L,2/L folded; Im(DC) col zeroed
//                        because pocketfft irfft ignores Im of the DC bin)
// R3 changes vs R2 (node count 8->6, middle-stage traffic cut):
//   * k_init also converts Wv,Wo -> bf16 (removes x4-duplicated fp32 W reads in GEMMs)
//   * gemm1+bias+cmul fused into ONE full-K kernel, zero LDS: A and W are K-contiguous
//     row-major so MFMA fragments load straight from global; C-layout row pairs
//     (2k,2k+1) live in the same lane quad -> cmul is register-local
//   * gemm2 writes Z bf16 directly (k_cmul, k_reduce8, P1, P2 all deleted)

typedef __attribute__((ext_vector_type(8))) short bf16x8;
typedef __attribute__((ext_vector_type(8))) unsigned short ushort8;
typedef __attribute__((ext_vector_type(4))) float f32x4;

__device__ __forceinline__ unsigned short f2bf(float x) {
    union { float f; unsigned int u; } c; c.f = x;
    unsigned int u = c.u + 0x7FFFu + ((c.u >> 16) & 1u);   // RNE
    return (unsigned short)(u >> 16);
}

// ---------------------------------------------------------------------------
// init: F[64][4096] bf16, G[4096][64] bf16, Wvb/Wob bf16 copies
// grid 8192 x 256 (2M threads)
// ---------------------------------------------------------------------------
__global__ __launch_bounds__(256) void k_init(const float* __restrict__ Wv,
                                              const float* __restrict__ Wo,
                                              unsigned short* __restrict__ F,
                                              unsigned short* __restrict__ G,
                                              unsigned short* __restrict__ Wvb,
                                              unsigned short* __restrict__ Wob) {
    int idx = blockIdx.x * 256 + threadIdx.x;        // 0..2097151
    const float w0 = 1.5339807878856412e-3f;          // 2*pi/4096
    if (idx < 262144) {
        {   // F[j][t]: j=2k -> cos(2pi k t/L), j=2k+1 -> -sin(2pi k t/L)
            int j = idx >> 12, t = idx & 4095, k = j >> 1;
            int r = (k * t) & 4095;
            float s, c; sincosf((float)r * w0, &s, &c);
            F[idx] = f2bf((j & 1) ? -s : c);
        }
        {   // G[t][j]: j=2k -> ck*cos, j=2k+1 -> -ck*sin (0 for k==0), ck=(k?2:1)/L
            int j = idx & 63, k = j >> 1;
            int t = idx >> 6;
            int r = (k * t) & 4095;
            float s, c; sincosf((float)r * w0, &s, &c);
            float ck = (k == 0) ? (1.0f / 4096.0f) : (2.0f / 4096.0f);
            float v = (j & 1) ? ((k == 0) ? 0.0f : -ck * s) : ck * c;
            G[idx] = f2bf(v);
        }
    }
    if (idx < 1048576) Wvb[idx] = f2bf(Wv[idx]);
    else               Wob[idx - 1048576] = f2bf(Wo[idx - 1048576]);
}

// ---------------------------------------------------------------------------
// K1: P0[kp][b][64 j][1024 n] = F[64 j][t-chunk] @ q[b][t-chunk][32 n]
// grid = b(4) x ntile(32) x kp(16), 1 wave per block, plain fp32 partial stores
// ---------------------------------------------------------------------------
__global__ __launch_bounds__(64) void k_dft_fwd(const float* __restrict__ q,
                                                const unsigned short* __restrict__ F,
                                                float* __restrict__ P0) {
    __shared__ __align__(16) unsigned short Ft[64 * 40];  // [j][t] pad->40
    __shared__ __align__(16) unsigned short qT[32 * 40];  // [n][t] pad->40
    int blk = blockIdx.x;
    int kp = blk & 15, nt = (blk >> 4) & 31, b = blk >> 9;
    int n0 = nt * 32, t0 = kp * 256;
    int lane = threadIdx.x;
    int lm = lane & 15, q4 = lane >> 4;
    int nn4 = (lane & 7) * 4, th = lane >> 3;
    f32x4 acc[4][2] = {};
    for (int ks = 0; ks < 8; ++ks) {
        int tb = t0 + ks * 32;
        #pragma unroll
        for (int i = 0; i < 4; ++i) {
            ushort8 v = *(const ushort8*)&F[lane * 4096 + tb + i * 8];
            *(ushort8*)&Ft[lane * 40 + i * 8] = v;
        }
        #pragma unroll
        for (int r2 = 0; r2 < 2; ++r2) {
            int p = r2 * 8 + th;
            const float* row0 = &q[(size_t)(b * 4096 + tb + 2 * p) * 1024 + n0 + nn4];
            float4 v0 = *(const float4*)row0;
            float4 v1 = *(const float4*)(row0 + 1024);
            #pragma unroll
            for (int i = 0; i < 4; ++i) {
                float a = (&v0.x)[i], c = (&v1.x)[i];
                unsigned int u = (unsigned int)f2bf(a) | ((unsigned int)f2bf(c) << 16);
                *(unsigned int*)&qT[(nn4 + i) * 40 + 2 * p] = u;
            }
        }
        __syncthreads();
        bf16x8 af[4], bq[2];
        #pragma unroll
        for (int mt = 0; mt < 4; ++mt)
            af[mt] = *(const bf16x8*)&Ft[(mt * 16 + lm) * 40 + q4 * 8];
        #pragma unroll
        for (int ntt = 0; ntt < 2; ++ntt)
            bq[ntt] = *(const bf16x8*)&qT[(ntt * 16 + lm) * 40 + q4 * 8];
        #pragma unroll
        for (int mt = 0; mt < 4; ++mt)
            #pragma unroll
            for (int ntt = 0; ntt < 2; ++ntt)
                acc[mt][ntt] = __builtin_amdgcn_mfma_f32_16x16x32_bf16(
                    af[mt], bq[ntt], acc[mt][ntt], 0, 0, 0);
        __syncthreads();
    }
    size_t base = (size_t)kp * 262144 + (size_t)b * 65536;
    #pragma unroll
    for (int mt = 0; mt < 4; ++mt)
        #pragma unroll
        for (int ntt = 0; ntt < 2; ++ntt)
            #pragma unroll
            for (int r = 0; r < 4; ++r) {
                int j = mt * 16 + q4 * 4 + r;
                int n = n0 + ntt * 16 + lm;
                P0[base + j * 1024 + n] = acc[mt][ntt][r];
            }
}

// ---------------------------------------------------------------------------
// k_red16: A_bf16[4*64*1024] = sum of 16 fp32 partials (float4 loads)
// ---------------------------------------------------------------------------
__global__ __launch_bounds__(256) void k_red16(const float* __restrict__ P0,
                                               unsigned short* __restrict__ Abf) {
    int idx = (blockIdx.x * 256 + threadIdx.x) * 4;   // 262144 elems / 4
    float4 s = make_float4(0.f, 0.f, 0.f, 0.f);
    #pragma unroll
    for (int p = 0; p < 16; ++p) {
        float4 v = *(const float4*)&P0[(size_t)p * 262144 + idx];
        s.x += v.x; s.y += v.y; s.z += v.z; s.w += v.w;
    }
    ushort4 o;
    o.x = f2bf(s.x); o.y = f2bf(s.y); o.z = f2bf(s.z); o.w = f2bf(s.w);
    *(ushort4*)&Abf[idx] = o;
}

// ---------------------------------------------------------------------------
// k_gemm_small<CMUL>: Out[256 m][1024 n] = Ain[256 m][1024 k] @ Wb[1024 n][1024 k]^T
// Full-K, zero LDS: fragments load straight from global (K-contiguous rows).
// grid = b(4) x nt(16) = 64 blocks; 4 waves each own a 16-col sub-tile.
// CMUL=1: + DC bias, x (wr + i wi) register-local (row pairs share a lane quad).
// ---------------------------------------------------------------------------
template<int CMUL>
__global__ __launch_bounds__(256) void k_gemm_small(const unsigned short* __restrict__ Ain,
                                                    const unsigned short* __restrict__ Wb,
                                                    const float* __restrict__ bv,
                                                    const float* __restrict__ wr,
                                                    const float* __restrict__ wi,
                                                    unsigned short* __restrict__ Out) {
    int blk = blockIdx.x;
    int b = blk >> 4, nt = blk & 15;
    int tid = threadIdx.x, lane = tid & 63, w = tid >> 6;
    int lm = lane & 15, q4 = lane >> 4;
    int gn = nt * 64 + w * 16 + lm;                    // this lane's output col
    const unsigned short* arow = &Ain[(size_t)(b * 64) * 1024 + q4 * 8];
    const unsigned short* brow = &Wb[(size_t)gn * 1024 + q4 * 8];
    f32x4 acc[4] = {};
    #pragma unroll 2
    for (int it = 0; it < 32; ++it) {
        int kb = it * 32;
        bf16x8 bfr = *(const bf16x8*)&brow[kb];
        #pragma unroll
        for (int mt4 = 0; mt4 < 4; ++mt4) {
            bf16x8 afr = *(const bf16x8*)&arow[(mt4 * 16 + lm) * 1024 + kb];
            acc[mt4] = __builtin_amdgcn_mfma_f32_16x16x32_bf16(afr, bfr, acc[mt4], 0, 0, 0);
        }
    }
    if (CMUL) {
        int h = gn >> 6, dh = gn & 63;
        #pragma unroll
        for (int mt4 = 0; mt4 < 4; ++mt4) {
            int m0 = mt4 * 16 + q4 * 4;                // even
            #pragma unroll
            for (int pp = 0; pp < 2; ++pp) {
                int m = m0 + 2 * pp, k = m >> 1;
                float re = acc[mt4][2 * pp], im = acc[mt4][2 * pp + 1];
                if (m == 0) re += 4096.0f * bv[gn];    // bias only feeds the DC bin
                float a = wr[(h * 32 + k) * 64 + dh];
                float c = wi[(h * 32 + k) * 64 + dh];
                Out[(size_t)(b * 64 + m) * 1024 + gn]     = f2bf(re * a - im * c);
                Out[(size_t)(b * 64 + m + 1) * 1024 + gn] = f2bf(re * c + im * a);
            }
        }
    } else {
        #pragma unroll
        for (int mt4 = 0; mt4 < 4; ++mt4)
            #pragma unroll
            for (int r = 0; r < 4; ++r)
                Out[(size_t)(b * 64 + mt4 * 16 + q4 * 4 + r) * 1024 + gn] = f2bf(acc[mt4][r]);
    }
}

// ---------------------------------------------------------------------------
// K5: out[b][t][n] = G[t][64] @ Z[b][64][n] + bo[n]   (fp32 out, 64 MB write)
// grid = b(4) x ttile(32) x ntile(8); block 256 thr = 4 waves of 64x64
// ---------------------------------------------------------------------------
__global__ __launch_bounds__(256) void k_dft_inv(const unsigned short* __restrict__ G,
                                                 const unsigned short* __restrict__ Zb,
                                                 const float* __restrict__ bo,
                                                 float* __restrict__ out) {
    __shared__ __align__(16) unsigned short Gt[128 * 72];  // [t][j] pad->72
    __shared__ __align__(16) unsigned short ZT[128 * 72];  // [n][j] pad->72
    int blk = blockIdx.x;
    int nt = blk & 7, tt = (blk >> 3) & 31, b = blk >> 8;
    int n0 = nt * 128, t0 = tt * 128;
    int tid = threadIdx.x, lane = tid & 63, w = tid >> 6;
    int lm = lane & 15, q4 = lane >> 4;
    {
        int ttl = tid >> 1, jj = (tid & 1) * 32;
        #pragma unroll
        for (int i = 0; i < 4; ++i) {
            ushort8 v = *(const ushort8*)&G[(t0 + ttl) * 64 + jj + i * 8];
            *(ushort8*)&Gt[ttl * 72 + jj + i * 8] = v;
        }
    }
    {
        int jp = tid & 31, hi = tid >> 5;
        int j = jp * 2, nn0 = hi * 16;
        const unsigned short* r0 = &Zb[(b * 64 + j) * 1024 + n0 + nn0];
        const unsigned short* r1 = &Zb[(b * 64 + j + 1) * 1024 + n0 + nn0];
        ushort8 a0 = *(const ushort8*)r0, a1 = *(const ushort8*)(r0 + 8);
        ushort8 b0 = *(const ushort8*)r1, b1 = *(const ushort8*)(r1 + 8);
        #pragma unroll
        for (int i = 0; i < 8; ++i) {
            unsigned int v = (unsigned int)a0[i] | ((unsigned int)b0[i] << 16);
            *(unsigned int*)&ZT[(nn0 + i) * 72 + j] = v;
        }
        #pragma unroll
        for (int i = 0; i < 8; ++i) {
            unsigned int v = (unsigned int)a1[i] | ((unsigned int)b1[i] << 16);
            *(unsigned int*)&ZT[(nn0 + 8 + i) * 72 + j] = v;
        }
    }
    __syncthreads();
    int wt0 = (w >> 1) * 64, wn0 = (w & 1) * 64;
    f32x4 acc[4][4] = {};
    #pragma unroll
    for (int ks = 0; ks < 2; ++ks) {
        bf16x8 af[4], bf[4];
        #pragma unroll
        for (int mt = 0; mt < 4; ++mt)
            af[mt] = *(const bf16x8*)&Gt[(wt0 + mt * 16 + lm) * 72 + ks * 32 + q4 * 8];
        #pragma unroll
        for (int ntt = 0; ntt < 4; ++ntt)
            bf[ntt] = *(const bf16x8*)&ZT[(wn0 + ntt * 16 + lm) * 72 + ks * 32 + q4 * 8];
        #pragma unroll
        for (int mt = 0; mt < 4; ++mt)
            #pragma unroll
            for (int ntt = 0; ntt < 4; ++ntt)
                acc[mt][ntt] = __builtin_amdgcn_mfma_f32_16x16x32_bf16(
                    af[mt], bf[ntt], acc[mt][ntt], 0, 0, 0);
    }
    #pragma unroll
    for (int ntt = 0; ntt < 4; ++ntt) {
        int n = n0 + wn0 + ntt * 16 + lm;
        float bov = bo[n];
        #pragma unroll
        for (int mt = 0; mt < 4; ++mt)
            #pragma unroll
            for (int r = 0; r < 4; ++r) {
                int t = t0 + wt0 + mt * 16 + q4 * 4 + r;
                out[(size_t)(b * 4096 + t) * 1024 + n] = acc[mt][ntt][r] + bov;
            }
    }
}

// ---------------------------------------------------------------------------
extern "C" void kernel_launch(void* const* d_in, const int* in_sizes, int n_in,
                              void* d_out, int out_size, void* d_ws, size_t ws_size,
                              hipStream_t stream) {
    const float* q  = (const float*)d_in[0];
    const float* Wv = (const float*)d_in[1];
    const float* bv = (const float*)d_in[2];
    const float* Wo = (const float*)d_in[3];
    const float* bo = (const float*)d_in[4];
    const float* wr = (const float*)d_in[5];
    const float* wi = (const float*)d_in[6];
    float* out = (float*)d_out;

    char* ws = (char*)d_ws;
    unsigned short* F   = (unsigned short*)(ws);                            // 512 KB
    unsigned short* G   = (unsigned short*)(ws + (512 << 10));              // 512 KB
    unsigned short* Abf = (unsigned short*)(ws + (1 << 20));                // 512 KB
    unsigned short* Y   = (unsigned short*)(ws + (1 << 20) + (512 << 10));  // 512 KB
    unsigned short* Zb  = (unsigned short*)(ws + (2 << 20));                // 512 KB
    unsigned short* Wvb = (unsigned short*)(ws + (3u << 20));               // 2 MB
    unsigned short* Wob = (unsigned short*)(ws + (5u << 20));               // 2 MB
    float*          P0  = (float*)(ws + (8u << 20));                        // 16 MB

    hipLaunchKernelGGL(k_init,    dim3(8192), dim3(256), 0, stream, Wv, Wo, F, G, Wvb, Wob);
    hipLaunchKernelGGL(k_dft_fwd, dim3(2048), dim3(64),  0, stream, q, F, P0);
    hipLaunchKernelGGL(k_red16,   dim3(256),  dim3(256), 0, stream, P0, Abf);
    hipLaunchKernelGGL((k_gemm_small<1>), dim3(64), dim3(256), 0, stream, Abf, Wvb, bv, wr, wi, Y);
    hipLaunchKernelGGL((k_gemm_small<0>), dim3(64), dim3(256), 0, stream, Y, Wob, bv, wr, wi, Zb);
    hipLaunchKernelGGL(k_dft_inv, dim3(1024), dim3(256), 0, stream, G, Zb, bo, out);
}

// Round 4
// 177.621 us; speedup vs baseline: 1.0841x; 1.0841x over previous
//
#include <hip/hip_runtime.h>
#include <math.h>

// Problem constants: B=4, L=4096, D_MODEL=1024, N_HEADS=16, D_HEAD=64, MODES=32
// Rank-64 reassociation (only 32 complex modes survive truncation):
//   A  = F @ q          [4][64][1024] fp32, atomic split-K over t (F: 64x4096 DFT rows)
//   C  = A @ Wv^T       fp32, atomic split-K (bias folded into cmul stage below)
//   Y  = cmul(C)        fused into gemm2's A-staging: row pairs (2k,2k+1) rotated by
//                       (wr+i wi), DC-real row gets +4096*bv (sum_t cos = 0 for k!=0)
//   Z  = Y @ Wo^T       fp32, atomic split-K
//   out= G @ Z + bo     (G: 4096x64 inverse-DFT cols, 1/L & 2/L folded, Im(DC) col = 0
//                        because pocketfft irfft ignores Im of the DC bin)
// R4 vs R3: revert middle to split-K+LDS (R2's measured-good shape) with atomicAdd
// epilogues (R1 proved contended fp32 atomics are cheap); cmul fused into gemm2
// staging; fp32->bf16 conversions fused into consumers. 5 kernels, no partial buffers.

typedef __attribute__((ext_vector_type(8))) short bf16x8;
typedef __attribute__((ext_vector_type(8))) unsigned short ushort8;
typedef __attribute__((ext_vector_type(4))) float f32x4;

__device__ __forceinline__ unsigned short f2bf(float x) {
    union { float f; unsigned int u; } c; c.f = x;
    unsigned int u = c.u + 0x7FFFu + ((c.u >> 16) & 1u);   // RNE
    return (unsigned short)(u >> 16);
}

// ---------------------------------------------------------------------------
// init: F[64][4096] bf16, G[4096][64] bf16, Wvb/Wob bf16, zero Af/Cf/Zf fp32
// grid 8192 x 256 (2M threads)
// ---------------------------------------------------------------------------
__global__ __launch_bounds__(256) void k_init(const float* __restrict__ Wv,
                                              const float* __restrict__ Wo,
                                              unsigned short* __restrict__ F,
                                              unsigned short* __restrict__ G,
                                              unsigned short* __restrict__ Wvb,
                                              unsigned short* __restrict__ Wob,
                                              float* __restrict__ Af,
                                              float* __restrict__ Cf,
                                              float* __restrict__ Zf) {
    int idx = blockIdx.x * 256 + threadIdx.x;        // 0..2097151
    const float w0 = 1.5339807878856412e-3f;          // 2*pi/4096
    if (idx < 262144) {
        {   // F[j][t]: j=2k -> cos(2pi k t/L), j=2k+1 -> -sin(2pi k t/L)
            int j = idx >> 12, t = idx & 4095, k = j >> 1;
            int r = (k * t) & 4095;
            float s, c; sincosf((float)r * w0, &s, &c);
            F[idx] = f2bf((j & 1) ? -s : c);
        }
        {   // G[t][j]: j=2k -> ck*cos, j=2k+1 -> -ck*sin (0 for k==0), ck=(k?2:1)/L
            int j = idx & 63, k = j >> 1;
            int t = idx >> 6;
            int r = (k * t) & 4095;
            float s, c; sincosf((float)r * w0, &s, &c);
            float ck = (k == 0) ? (1.0f / 4096.0f) : (2.0f / 4096.0f);
            float v = (j & 1) ? ((k == 0) ? 0.0f : -ck * s) : ck * c;
            G[idx] = f2bf(v);
        }
        Af[idx] = 0.0f; Cf[idx] = 0.0f; Zf[idx] = 0.0f;
    }
    if (idx < 1048576) Wvb[idx] = f2bf(Wv[idx]);
    else               Wob[idx - 1048576] = f2bf(Wo[idx - 1048576]);
}

// ---------------------------------------------------------------------------
// K1: Af[b][64 j][1024 n] += F[64 j][t-chunk] @ q[b][t-chunk][32 n]
// grid = b(4) x ntile(32) x kp(16), 1 wave per block, fp32 atomicAdd epilogue
// ---------------------------------------------------------------------------
__global__ __launch_bounds__(64) void k_dft_fwd(const float* __restrict__ q,
                                                const unsigned short* __restrict__ F,
                                                float* __restrict__ Af) {
    __shared__ __align__(16) unsigned short Ft[64 * 40];  // [j][t] pad->40
    __shared__ __align__(16) unsigned short qT[32 * 40];  // [n][t] pad->40
    int blk = blockIdx.x;
    int kp = blk & 15, nt = (blk >> 4) & 31, b = blk >> 9;
    int n0 = nt * 32, t0 = kp * 256;
    int lane = threadIdx.x;
    int lm = lane & 15, q4 = lane >> 4;
    int nn4 = (lane & 7) * 4, th = lane >> 3;
    f32x4 acc[4][2] = {};
    for (int ks = 0; ks < 8; ++ks) {
        int tb = t0 + ks * 32;
        #pragma unroll
        for (int i = 0; i < 4; ++i) {
            ushort8 v = *(const ushort8*)&F[lane * 4096 + tb + i * 8];
            *(ushort8*)&Ft[lane * 40 + i * 8] = v;
        }
        #pragma unroll
        for (int r2 = 0; r2 < 2; ++r2) {
            int p = r2 * 8 + th;
            const float* row0 = &q[(size_t)(b * 4096 + tb + 2 * p) * 1024 + n0 + nn4];
            float4 v0 = *(const float4*)row0;
            float4 v1 = *(const float4*)(row0 + 1024);
            #pragma unroll
            for (int i = 0; i < 4; ++i) {
                float a = (&v0.x)[i], c = (&v1.x)[i];
                unsigned int u = (unsigned int)f2bf(a) | ((unsigned int)f2bf(c) << 16);
                *(unsigned int*)&qT[(nn4 + i) * 40 + 2 * p] = u;
            }
        }
        __syncthreads();
        bf16x8 af[4], bq[2];
        #pragma unroll
        for (int mt = 0; mt < 4; ++mt)
            af[mt] = *(const bf16x8*)&Ft[(mt * 16 + lm) * 40 + q4 * 8];
        #pragma unroll
        for (int ntt = 0; ntt < 2; ++ntt)
            bq[ntt] = *(const bf16x8*)&qT[(ntt * 16 + lm) * 40 + q4 * 8];
        #pragma unroll
        for (int mt = 0; mt < 4; ++mt)
            #pragma unroll
            for (int ntt = 0; ntt < 2; ++ntt)
                acc[mt][ntt] = __builtin_amdgcn_mfma_f32_16x16x32_bf16(
                    af[mt], bq[ntt], acc[mt][ntt], 0, 0, 0);
        __syncthreads();
    }
    #pragma unroll
    for (int mt = 0; mt < 4; ++mt)
        #pragma unroll
        for (int ntt = 0; ntt < 2; ++ntt)
            #pragma unroll
            for (int r = 0; r < 4; ++r) {
                int j = mt * 16 + q4 * 4 + r;
                int n = n0 + ntt * 16 + lm;
                atomicAdd(&Af[(b * 64 + j) * 1024 + n], acc[mt][ntt][r]);
            }
}

// ---------------------------------------------------------------------------
// k_gemm_at<FUSE>: Pout[256 m][1024 n] += Ain[256 m][k-chunk] @ Wb[1024 n][k-chunk]^T
// grid = mt(4) x nt(8) x kp(8) = 256 blocks; Ain fp32; Wb bf16; atomicAdd epilogue.
// FUSE=1: A-staging applies DC bias + complex rotation (wr,wi) on row pairs.
// ---------------------------------------------------------------------------
template<int FUSE>
__global__ __launch_bounds__(256) void k_gemm_at(const float* __restrict__ Ain,
                                                 const unsigned short* __restrict__ Wb,
                                                 const float* __restrict__ bv,
                                                 const float* __restrict__ wr,
                                                 const float* __restrict__ wi,
                                                 float* __restrict__ Pout) {
    __shared__ __align__(16) unsigned short At[64 * 40];
    __shared__ __align__(16) unsigned short Wt[128 * 40];
    int blk = blockIdx.x;
    int kp = blk & 7, nt = (blk >> 3) & 7, mt = blk >> 6;
    int m0 = mt * 64, n0 = nt * 128, k0 = kp * 128;
    int tid = threadIdx.x, lane = tid & 63, w = tid >> 6;
    int lm = lane & 15, q4 = lane >> 4;
    int ma = tid >> 2, ka = (tid & 3) * 8;
    int nw = tid >> 1, kw = (tid & 1) * 16;
    f32x4 acc[4][2] = {};
    for (int ks = 0; ks < 4; ++ks) {
        int kb = k0 + ks * 32;
        if (!FUSE) {
            const float* ap = &Ain[(size_t)(m0 + ma) * 1024 + kb + ka];
            float4 x0 = ((const float4*)ap)[0], x1 = ((const float4*)ap)[1];
            ushort8 v;
            v[0]=f2bf(x0.x); v[1]=f2bf(x0.y); v[2]=f2bf(x0.z); v[3]=f2bf(x0.w);
            v[4]=f2bf(x1.x); v[5]=f2bf(x1.y); v[6]=f2bf(x1.z); v[7]=f2bf(x1.w);
            *(ushort8*)&At[ma * 40 + ka] = v;
        } else {
            // row pair (2k, 2k+1); col = kb+ka..+8 stays in one 64-wide head block
            int j = ma, je = j & ~1, kmode = je >> 1;
            int col = kb + ka, h = col >> 6, dh = col & 63;
            const float* re_p = &Ain[(size_t)(m0 + je) * 1024 + col];
            float4 e0 = ((const float4*)re_p)[0], e1 = ((const float4*)re_p)[1];
            float4 o0 = ((const float4*)(re_p + 1024))[0], o1 = ((const float4*)(re_p + 1024))[1];
            const float* wrp = &wr[(h * 32 + kmode) * 64 + dh];
            const float* wip = &wi[(h * 32 + kmode) * 64 + dh];
            float4 a0 = ((const float4*)wrp)[0], a1 = ((const float4*)wrp)[1];
            float4 c0 = ((const float4*)wip)[0], c1 = ((const float4*)wip)[1];
            float ev[8], ov[8], av[8], cv[8];
            #pragma unroll
            for (int i = 0; i < 4; ++i) {
                ev[i] = (&e0.x)[i]; ev[4+i] = (&e1.x)[i];
                ov[i] = (&o0.x)[i]; ov[4+i] = (&o1.x)[i];
                av[i] = (&a0.x)[i]; av[4+i] = (&a1.x)[i];
                cv[i] = (&c0.x)[i]; cv[4+i] = (&c1.x)[i];
            }
            if (kmode == 0) {   // DC real row gets 4096*bv
                float4 b0 = ((const float4*)&bv[col])[0], b1 = ((const float4*)&bv[col])[1];
                #pragma unroll
                for (int i = 0; i < 4; ++i) {
                    ev[i]   += 4096.0f * (&b0.x)[i];
                    ev[4+i] += 4096.0f * (&b1.x)[i];
                }
            }
            ushort8 v;
            #pragma unroll
            for (int i = 0; i < 8; ++i) {
                float y = (j & 1) ? (ev[i] * cv[i] + ov[i] * av[i])
                                  : (ev[i] * av[i] - ov[i] * cv[i]);
                v[i] = f2bf(y);
            }
            *(ushort8*)&At[ma * 40 + ka] = v;
        }
        {
            const unsigned short* wp = &Wb[(size_t)(n0 + nw) * 1024 + kb + kw];
            ushort8 v0 = ((const ushort8*)wp)[0], v1 = ((const ushort8*)wp)[1];
            *(ushort8*)&Wt[nw * 40 + kw]     = v0;
            *(ushort8*)&Wt[nw * 40 + kw + 8] = v1;
        }
        __syncthreads();
        bf16x8 af[4], bf[2];
        #pragma unroll
        for (int mti = 0; mti < 4; ++mti)
            af[mti] = *(const bf16x8*)&At[(mti * 16 + lm) * 40 + q4 * 8];
        #pragma unroll
        for (int ntt = 0; ntt < 2; ++ntt)
            bf[ntt] = *(const bf16x8*)&Wt[(w * 32 + ntt * 16 + lm) * 40 + q4 * 8];
        #pragma unroll
        for (int mti = 0; mti < 4; ++mti)
            #pragma unroll
            for (int ntt = 0; ntt < 2; ++ntt)
                acc[mti][ntt] = __builtin_amdgcn_mfma_f32_16x16x32_bf16(
                    af[mti], bf[ntt], acc[mti][ntt], 0, 0, 0);
        __syncthreads();
    }
    #pragma unroll
    for (int mti = 0; mti < 4; ++mti)
        #pragma unroll
        for (int ntt = 0; ntt < 2; ++ntt)
            #pragma unroll
            for (int r = 0; r < 4; ++r) {
                int m = m0 + mti * 16 + q4 * 4 + r;
                int n = n0 + w * 32 + ntt * 16 + lm;
                atomicAdd(&Pout[(size_t)m * 1024 + n], acc[mti][ntt][r]);
            }
}

// ---------------------------------------------------------------------------
// K5: out[b][t][n] = G[t][64] @ Zf[b][64][n] + bo[n]   (fp32 out, 64 MB write)
// grid = b(4) x ttile(32) x ntile(8); block 256 thr = 4 waves of 64x64
// Zf is fp32; conversion to bf16 fused into the transpose staging.
// ---------------------------------------------------------------------------
__global__ __launch_bounds__(256) void k_dft_inv(const unsigned short* __restrict__ G,
                                                 const float* __restrict__ Zf,
                                                 const float* __restrict__ bo,
                                                 float* __restrict__ out) {
    __shared__ __align__(16) unsigned short Gt[128 * 72];  // [t][j] pad->72
    __shared__ __align__(16) unsigned short ZT[128 * 72];  // [n][j] pad->72
    int blk = blockIdx.x;
    int nt = blk & 7, tt = (blk >> 3) & 31, b = blk >> 8;
    int n0 = nt * 128, t0 = tt * 128;
    int tid = threadIdx.x, lane = tid & 63, w = tid >> 6;
    int lm = lane & 15, q4 = lane >> 4;
    {
        int ttl = tid >> 1, jj = (tid & 1) * 32;
        #pragma unroll
        for (int i = 0; i < 4; ++i) {
            ushort8 v = *(const ushort8*)&G[(t0 + ttl) * 64 + jj + i * 8];
            *(ushort8*)&Gt[ttl * 72 + jj + i * 8] = v;
        }
    }
    {
        int jp = tid & 31, hi = tid >> 5;          // j pair, n-chunk
        int j = jp * 2, nn0 = hi * 16;
        const float* r0 = &Zf[(size_t)(b * 64 + j) * 1024 + n0 + nn0];
        const float* r1 = r0 + 1024;
        float av[16], bvv[16];
        #pragma unroll
        for (int i4 = 0; i4 < 4; ++i4) {
            float4 x = ((const float4*)r0)[i4], y = ((const float4*)r1)[i4];
            #pragma unroll
            for (int i = 0; i < 4; ++i) { av[i4*4+i] = (&x.x)[i]; bvv[i4*4+i] = (&y.x)[i]; }
        }
        #pragma unroll
        for (int i = 0; i < 16; ++i) {
            unsigned int v = (unsigned int)f2bf(av[i]) | ((unsigned int)f2bf(bvv[i]) << 16);
            *(unsigned int*)&ZT[(nn0 + i) * 72 + j] = v;
        }
    }
    __syncthreads();
    int wt0 = (w >> 1) * 64, wn0 = (w & 1) * 64;
    f32x4 acc[4][4] = {};
    #pragma unroll
    for (int ks = 0; ks < 2; ++ks) {
        bf16x8 af[4], bf[4];
        #pragma unroll
        for (int mt = 0; mt < 4; ++mt)
            af[mt] = *(const bf16x8*)&Gt[(wt0 + mt * 16 + lm) * 72 + ks * 32 + q4 * 8];
        #pragma unroll
        for (int ntt = 0; ntt < 4; ++ntt)
            bf[ntt] = *(const bf16x8*)&ZT[(wn0 + ntt * 16 + lm) * 72 + ks * 32 + q4 * 8];
        #pragma unroll
        for (int mt = 0; mt < 4; ++mt)
            #pragma unroll
            for (int ntt = 0; ntt < 4; ++ntt)
                acc[mt][ntt] = __builtin_amdgcn_mfma_f32_16x16x32_bf16(
                    af[mt], bf[ntt], acc[mt][ntt], 0, 0, 0);
    }
    #pragma unroll
    for (int ntt = 0; ntt < 4; ++ntt) {
        int n = n0 + wn0 + ntt * 16 + lm;
        float bov = bo[n];
        #pragma unroll
        for (int mt = 0; mt < 4; ++mt)
            #pragma unroll
            for (int r = 0; r < 4; ++r) {
                int t = t0 + wt0 + mt * 16 + q4 * 4 + r;
                out[(size_t)(b * 4096 + t) * 1024 + n] = acc[mt][ntt][r] + bov;
            }
    }
}

// ---------------------------------------------------------------------------
extern "C" void kernel_launch(void* const* d_in, const int* in_sizes, int n_in,
                              void* d_out, int out_size, void* d_ws, size_t ws_size,
                              hipStream_t stream) {
    const float* q  = (const float*)d_in[0];
    const float* Wv = (const float*)d_in[1];
    const float* bv = (const float*)d_in[2];
    const float* Wo = (const float*)d_in[3];
    const float* bo = (const float*)d_in[4];
    const float* wr = (const float*)d_in[5];
    const float* wi = (const float*)d_in[6];
    float* out = (float*)d_out;

    char* ws = (char*)d_ws;
    unsigned short* F   = (unsigned short*)(ws);                 // 512 KB
    unsigned short* G   = (unsigned short*)(ws + (512 << 10));   // 512 KB
    float*          Af  = (float*)(ws + (1u << 20));             // 1 MB
    float*          Cf  = (float*)(ws + (2u << 20));             // 1 MB
    float*          Zf  = (float*)(ws + (3u << 20));             // 1 MB
    unsigned short* Wvb = (unsigned short*)(ws + (4u << 20));    // 2 MB
    unsigned short* Wob = (unsigned short*)(ws + (6u << 20));    // 2 MB

    hipLaunchKernelGGL(k_init,    dim3(8192), dim3(256), 0, stream,
                       Wv, Wo, F, G, Wvb, Wob, Af, Cf, Zf);
    hipLaunchKernelGGL(k_dft_fwd, dim3(2048), dim3(64),  0, stream, q, F, Af);
    hipLaunchKernelGGL((k_gemm_at<0>), dim3(256), dim3(256), 0, stream,
                       Af, Wvb, bv, wr, wi, Cf);
    hipLaunchKernelGGL((k_gemm_at<1>), dim3(256), dim3(256), 0, stream,
                       Cf, Wob, bv, wr, wi, Zf);
    hipLaunchKernelGGL(k_dft_inv, dim3(1024), dim3(256), 0, stream, G, Zf, bo, out);
}

// Round 5
// 172.806 us; speedup vs baseline: 1.1143x; 1.0279x over previous
//
#include <hip/hip_runtime.h>
#include <math.h>

// Problem constants: B=4, L=4096, D_MODEL=1024, N_HEADS=16, D_HEAD=64, MODES=32
// Rank-64 reassociation (only 32 complex modes survive truncation):
//   A  = F @ q          [4][64][1024] fp32, atomic split-K over t (F: 64x4096 DFT rows)
//   C  = A @ Wv^T       split-K partials P1 (bias folded into cmul: DC bin += 4096*bv)
//   Y  = reduce8(P1) * (wr + i wi)   interleaved re/im rows, bf16
//   Z  = Y @ Wo^T       split-K partials P2, reduce8 -> bf16
//   out= G @ Z + bo     (G: 4096x64 inverse-DFT cols, 1/L & 2/L folded, Im(DC) col = 0
//                        because pocketfft irfft ignores Im of the DC bin)
// R5 = R1 champion structure (169.1 us) verbatim EXCEPT k_dft_fwd:
//   1-wave blocks -> __syncthreads removed entirely (wave-private LDS, in-order DS),
//   Ft/qT double-buffered + full unroll so next tile's global loads overlap MFMA.

typedef __attribute__((ext_vector_type(8))) short bf16x8;
typedef __attribute__((ext_vector_type(8))) unsigned short ushort8;
typedef __attribute__((ext_vector_type(4))) float f32x4;

__device__ __forceinline__ unsigned short f2bf(float x) {
    union { float f; unsigned int u; } c; c.f = x;
    unsigned int u = c.u + 0x7FFFu + ((c.u >> 16) & 1u);   // RNE
    return (unsigned short)(u >> 16);
}

// ---------------------------------------------------------------------------
// init: F[64][4096] bf16, G[4096][64] bf16, zero Af (262144 floats)
// ---------------------------------------------------------------------------
__global__ __launch_bounds__(256) void k_init(unsigned short* __restrict__ F,
                                              unsigned short* __restrict__ G,
                                              float* __restrict__ Af) {
    int idx = blockIdx.x * 256 + threadIdx.x;        // 0..262143
    const float w0 = 1.5339807878856412e-3f;          // 2*pi/4096
    {   // F[j][t]: j=2k -> cos(2pi k t/L), j=2k+1 -> -sin(2pi k t/L)
        int j = idx >> 12, t = idx & 4095, k = j >> 1;
        int r = (k * t) & 4095;
        float s, c; sincosf((float)r * w0, &s, &c);
        F[idx] = f2bf((j & 1) ? -s : c);
    }
    {   // G[t][j]: j=2k -> ck*cos, j=2k+1 -> -ck*sin (0 for k==0), ck = (k?2:1)/L
        int j = idx & 63, k = j >> 1;
        int t = idx >> 6;
        int r = (k * t) & 4095;
        float s, c; sincosf((float)r * w0, &s, &c);
        float ck = (k == 0) ? (1.0f / 4096.0f) : (2.0f / 4096.0f);
        float v = (j & 1) ? ((k == 0) ? 0.0f : -ck * s) : ck * c;
        G[idx] = f2bf(v);
    }
    Af[idx] = 0.0f;
}

// ---------------------------------------------------------------------------
// K1: Af[b][64 j][1024 n] += F[64 j][t-chunk] @ q[b][t-chunk][32 n]
// grid = b(4) x ntile(32) x kp(16), 1 wave/block. NO barriers (wave-private LDS),
// double-buffered tiles, fully unrolled so loads pipeline across iterations.
// ---------------------------------------------------------------------------
__global__ __launch_bounds__(64) void k_dft_fwd(const float* __restrict__ q,
                                                const unsigned short* __restrict__ F,
                                                float* __restrict__ Af) {
    __shared__ __align__(16) unsigned short Ft[2][64 * 40];  // [j][t] pad->40
    __shared__ __align__(16) unsigned short qT[2][32 * 40];  // [n][t] pad->40
    int blk = blockIdx.x;
    int kp = blk & 15, nt = (blk >> 4) & 31, b = blk >> 9;
    int n0 = nt * 32, t0 = kp * 256;
    int lane = threadIdx.x;
    int lm = lane & 15, q4 = lane >> 4;
    int nn4 = (lane & 7) * 4, th = lane >> 3;

    #define STAGE_TILE(KS, P)                                                     \
    {                                                                             \
        int tb = t0 + (KS) * 32;                                                  \
        _Pragma("unroll")                                                         \
        for (int i = 0; i < 4; ++i) {                                             \
            ushort8 v = *(const ushort8*)&F[lane * 4096 + tb + i * 8];            \
            *(ushort8*)&Ft[P][lane * 40 + i * 8] = v;                             \
        }                                                                         \
        _Pragma("unroll")                                                         \
        for (int r2 = 0; r2 < 2; ++r2) {                                          \
            int pr = r2 * 8 + th;                                                 \
            const float* row0 = &q[(size_t)(b * 4096 + tb + 2 * pr) * 1024 + n0 + nn4]; \
            float4 v0 = *(const float4*)row0;                                     \
            float4 v1 = *(const float4*)(row0 + 1024);                            \
            _Pragma("unroll")                                                     \
            for (int i = 0; i < 4; ++i) {                                         \
                float a = (&v0.x)[i], c = (&v1.x)[i];                             \
                unsigned int u = (unsigned int)f2bf(a) | ((unsigned int)f2bf(c) << 16); \
                *(unsigned int*)&qT[P][(nn4 + i) * 40 + 2 * pr] = u;              \
            }                                                                     \
        }                                                                         \
    }

    f32x4 acc[4][2] = {};
    STAGE_TILE(0, 0)
    #pragma unroll
    for (int ks = 0; ks < 8; ++ks) {
        int p = ks & 1;
        if (ks < 7) { STAGE_TILE(ks + 1, p ^ 1) }
        bf16x8 af[4], bq[2];
        #pragma unroll
        for (int mt = 0; mt < 4; ++mt)
            af[mt] = *(const bf16x8*)&Ft[p][(mt * 16 + lm) * 40 + q4 * 8];
        #pragma unroll
        for (int ntt = 0; ntt < 2; ++ntt)
            bq[ntt] = *(const bf16x8*)&qT[p][(ntt * 16 + lm) * 40 + q4 * 8];
        #pragma unroll
        for (int mt = 0; mt < 4; ++mt)
            #pragma unroll
            for (int ntt = 0; ntt < 2; ++ntt)
                acc[mt][ntt] = __builtin_amdgcn_mfma_f32_16x16x32_bf16(
                    af[mt], bq[ntt], acc[mt][ntt], 0, 0, 0);
    }
    #undef STAGE_TILE
    #pragma unroll
    for (int mt = 0; mt < 4; ++mt)
        #pragma unroll
        for (int ntt = 0; ntt < 2; ++ntt)
            #pragma unroll
            for (int r = 0; r < 4; ++r) {
                int j = mt * 16 + q4 * 4 + r;
                int n = n0 + ntt * 16 + lm;
                atomicAdd(&Af[(b * 64 + j) * 1024 + n], acc[mt][ntt][r]);
            }
}

// ---------------------------------------------------------------------------
// K2/K4: P[kp][256 m][1024 n] = Ain[256 m][k-chunk] @ Bmat[1024 n][k-chunk]^T
// grid = mt(4) x nt(8) x kp(8); block 256 thr; Ain fp32 (template 0) or bf16 (1)
// ---------------------------------------------------------------------------
template<int ABF16>
__global__ __launch_bounds__(256) void k_gemm_bt(const void* __restrict__ Ain,
                                                 const float* __restrict__ Bmat,
                                                 float* __restrict__ P) {
    __shared__ __align__(16) unsigned short At[64 * 40];
    __shared__ __align__(16) unsigned short Wt[128 * 40];
    int blk = blockIdx.x;
    int kp = blk & 7, nt = (blk >> 3) & 7, mt = blk >> 6;
    int m0 = mt * 64, n0 = nt * 128, k0 = kp * 128;
    int tid = threadIdx.x, lane = tid & 63, w = tid >> 6;
    int lm = lane & 15, q4 = lane >> 4;
    int ma = tid >> 2, ka = (tid & 3) * 8;
    int nw = tid >> 1, kw = (tid & 1) * 16;
    f32x4 acc[4][2] = {};
    for (int ks = 0; ks < 4; ++ks) {
        int kb = k0 + ks * 32;
        if (ABF16) {
            ushort8 v = *(const ushort8*)&((const unsigned short*)Ain)[(m0 + ma) * 1024 + kb + ka];
            *(ushort8*)&At[ma * 40 + ka] = v;
        } else {
            const float* Af = (const float*)Ain;
            float4 x0 = *(const float4*)&Af[(m0 + ma) * 1024 + kb + ka];
            float4 x1 = *(const float4*)&Af[(m0 + ma) * 1024 + kb + ka + 4];
            ushort8 v;
            v[0]=f2bf(x0.x); v[1]=f2bf(x0.y); v[2]=f2bf(x0.z); v[3]=f2bf(x0.w);
            v[4]=f2bf(x1.x); v[5]=f2bf(x1.y); v[6]=f2bf(x1.z); v[7]=f2bf(x1.w);
            *(ushort8*)&At[ma * 40 + ka] = v;
        }
        {
            const float4* wp = (const float4*)&Bmat[(n0 + nw) * 1024 + kb + kw];
            float4 x0 = wp[0], x1 = wp[1], x2 = wp[2], x3 = wp[3];
            ushort8 v0, v1;
            v0[0]=f2bf(x0.x); v0[1]=f2bf(x0.y); v0[2]=f2bf(x0.z); v0[3]=f2bf(x0.w);
            v0[4]=f2bf(x1.x); v0[5]=f2bf(x1.y); v0[6]=f2bf(x1.z); v0[7]=f2bf(x1.w);
            v1[0]=f2bf(x2.x); v1[1]=f2bf(x2.y); v1[2]=f2bf(x2.z); v1[3]=f2bf(x2.w);
            v1[4]=f2bf(x3.x); v1[5]=f2bf(x3.y); v1[6]=f2bf(x3.z); v1[7]=f2bf(x3.w);
            *(ushort8*)&Wt[nw * 40 + kw]     = v0;
            *(ushort8*)&Wt[nw * 40 + kw + 8] = v1;
        }
        __syncthreads();
        bf16x8 af[4], bf[2];
        #pragma unroll
        for (int mti = 0; mti < 4; ++mti)
            af[mti] = *(const bf16x8*)&At[(mti * 16 + lm) * 40 + q4 * 8];
        #pragma unroll
        for (int ntt = 0; ntt < 2; ++ntt)
            bf[ntt] = *(const bf16x8*)&Wt[(w * 32 + ntt * 16 + lm) * 40 + q4 * 8];
        #pragma unroll
        for (int mti = 0; mti < 4; ++mti)
            #pragma unroll
            for (int ntt = 0; ntt < 2; ++ntt)
                acc[mti][ntt] = __builtin_amdgcn_mfma_f32_16x16x32_bf16(
                    af[mti], bf[ntt], acc[mti][ntt], 0, 0, 0);
        __syncthreads();
    }
    #pragma unroll
    for (int mti = 0; mti < 4; ++mti)
        #pragma unroll
        for (int ntt = 0; ntt < 2; ++ntt)
            #pragma unroll
            for (int r = 0; r < 4; ++r) {
                int m = m0 + mti * 16 + q4 * 4 + r;
                int n = n0 + w * 32 + ntt * 16 + lm;
                P[(size_t)kp * 262144 + m * 1024 + n] = acc[mti][ntt][r];
            }
}

// ---------------------------------------------------------------------------
// K3: reduce 8 partials + mode-0 bias + complex multiply by w -> Y bf16
// ---------------------------------------------------------------------------
__global__ __launch_bounds__(256) void k_cmul(const float* __restrict__ P,
                                              const float* __restrict__ bv,
                                              const float* __restrict__ wr,
                                              const float* __restrict__ wi,
                                              unsigned short* __restrict__ Y) {
    int idx = blockIdx.x * 256 + threadIdx.x;     // 131072 = 4*32*1024
    int n = idx & 1023, k = (idx >> 10) & 31, b = idx >> 15;
    int rowr = (b * 64 + 2 * k) * 1024 + n;
    int rowi = rowr + 1024;
    float re = 0.f, im = 0.f;
    #pragma unroll
    for (int p = 0; p < 8; ++p) {
        re += P[(size_t)p * 262144 + rowr];
        im += P[(size_t)p * 262144 + rowi];
    }
    if (k == 0) re += 4096.0f * bv[n];            // bias only feeds the DC bin
    int h = n >> 6, dh = n & 63;
    float a = wr[(h * 32 + k) * 64 + dh];
    float c = wi[(h * 32 + k) * 64 + dh];
    Y[rowr] = f2bf(re * a - im * c);
    Y[rowi] = f2bf(re * c + im * a);
}

// ---------------------------------------------------------------------------
// K4.5: reduce 8 partials -> Z bf16 (float4 loads)
// ---------------------------------------------------------------------------
__global__ __launch_bounds__(256) void k_reduce8(const float* __restrict__ P,
                                                 unsigned short* __restrict__ Z) {
    int idx = (blockIdx.x * 256 + threadIdx.x) * 4;   // 262144 / 4
    float4 s = make_float4(0.f, 0.f, 0.f, 0.f);
    #pragma unroll
    for (int p = 0; p < 8; ++p) {
        float4 v = *(const float4*)&P[(size_t)p * 262144 + idx];
        s.x += v.x; s.y += v.y; s.z += v.z; s.w += v.w;
    }
    ushort4 o;
    o.x = f2bf(s.x); o.y = f2bf(s.y); o.z = f2bf(s.z); o.w = f2bf(s.w);
    *(ushort4*)&Z[idx] = o;
}

// ---------------------------------------------------------------------------
// K5: out[b][t][n] = G[t][64] @ Z[b][64][n] + bo[n]   (fp32 out, 64 MB write)
// grid = b(4) x ttile(32) x ntile(8); block 256 thr = 4 waves of 64x64
// ---------------------------------------------------------------------------
__global__ __launch_bounds__(256) void k_dft_inv(const unsigned short* __restrict__ G,
                                                 const unsigned short* __restrict__ Zb,
                                                 const float* __restrict__ bo,
                                                 float* __restrict__ out) {
    __shared__ __align__(16) unsigned short Gt[128 * 72];  // [t][j] pad->72
    __shared__ __align__(16) unsigned short ZT[128 * 72];  // [n][j] pad->72
    int blk = blockIdx.x;
    int nt = blk & 7, tt = (blk >> 3) & 31, b = blk >> 8;
    int n0 = nt * 128, t0 = tt * 128;
    int tid = threadIdx.x, lane = tid & 63, w = tid >> 6;
    int lm = lane & 15, q4 = lane >> 4;
    {
        int ttl = tid >> 1, jj = (tid & 1) * 32;
        #pragma unroll
        for (int i = 0; i < 4; ++i) {
            ushort8 v = *(const ushort8*)&G[(t0 + ttl) * 64 + jj + i * 8];
            *(ushort8*)&Gt[ttl * 72 + jj + i * 8] = v;
        }
    }
    {
        int jp = tid & 31, hi = tid >> 5;
        int j = jp * 2, nn0 = hi * 16;
        const unsigned short* r0 = &Zb[(b * 64 + j) * 1024 + n0 + nn0];
        const unsigned short* r1 = &Zb[(b * 64 + j + 1) * 1024 + n0 + nn0];
        ushort8 a0 = *(const ushort8*)r0, a1 = *(const ushort8*)(r0 + 8);
        ushort8 b0 = *(const ushort8*)r1, b1 = *(const ushort8*)(r1 + 8);
        #pragma unroll
        for (int i = 0; i < 8; ++i) {
            unsigned int v = (unsigned int)a0[i] | ((unsigned int)b0[i] << 16);
            *(unsigned int*)&ZT[(nn0 + i) * 72 + j] = v;
        }
        #pragma unroll
        for (int i = 0; i < 8; ++i) {
            unsigned int v = (unsigned int)a1[i] | ((unsigned int)b1[i] << 16);
            *(unsigned int*)&ZT[(nn0 + 8 + i) * 72 + j] = v;
        }
    }
    __syncthreads();
    int wt0 = (w >> 1) * 64, wn0 = (w & 1) * 64;
    f32x4 acc[4][4] = {};
    #pragma unroll
    for (int ks = 0; ks < 2; ++ks) {
        bf16x8 af[4], bf[4];
        #pragma unroll
        for (int mt = 0; mt < 4; ++mt)
            af[mt] = *(const bf16x8*)&Gt[(wt0 + mt * 16 + lm) * 72 + ks * 32 + q4 * 8];
        #pragma unroll
        for (int ntt = 0; ntt < 4; ++ntt)
            bf[ntt] = *(const bf16x8*)&ZT[(wn0 + ntt * 16 + lm) * 72 + ks * 32 + q4 * 8];
        #pragma unroll
        for (int mt = 0; mt < 4; ++mt)
            #pragma unroll
            for (int ntt = 0; ntt < 4; ++ntt)
                acc[mt][ntt] = __builtin_amdgcn_mfma_f32_16x16x32_bf16(
                    af[mt], bf[ntt], acc[mt][ntt], 0, 0, 0);
    }
    #pragma unroll
    for (int ntt = 0; ntt < 4; ++ntt) {
        int n = n0 + wn0 + ntt * 16 + lm;
        float bov = bo[n];
        #pragma unroll
        for (int mt = 0; mt < 4; ++mt)
            #pragma unroll
            for (int r = 0; r < 4; ++r) {
                int t = t0 + wt0 + mt * 16 + q4 * 4 + r;
                out[(size_t)(b * 4096 + t) * 1024 + n] = acc[mt][ntt][r] + bov;
            }
    }
}

// ---------------------------------------------------------------------------
extern "C" void kernel_launch(void* const* d_in, const int* in_sizes, int n_in,
                              void* d_out, int out_size, void* d_ws, size_t ws_size,
                              hipStream_t stream) {
    const float* q  = (const float*)d_in[0];
    const float* Wv = (const float*)d_in[1];
    const float* bv = (const float*)d_in[2];
    const float* Wo = (const float*)d_in[3];
    const float* bo = (const float*)d_in[4];
    const float* wr = (const float*)d_in[5];
    const float* wi = (const float*)d_in[6];
    float* out = (float*)d_out;

    char* ws = (char*)d_ws;
    unsigned short* F   = (unsigned short*)(ws);                            // 512 KB
    unsigned short* G   = (unsigned short*)(ws + (512 << 10));              // 512 KB
    float*          Af  = (float*)(ws + (1u << 20));                        // 1 MB
    unsigned short* Y   = (unsigned short*)(ws + (2u << 20));               // 512 KB
    unsigned short* Zb  = (unsigned short*)(ws + (2u << 20) + (512 << 10)); // 512 KB
    float*          P1  = (float*)(ws + (3u << 20));                        // 8 MB
    float*          P2  = (float*)(ws + (11u << 20));                       // 8 MB

    hipLaunchKernelGGL(k_init,    dim3(1024), dim3(256), 0, stream, F, G, Af);
    hipLaunchKernelGGL(k_dft_fwd, dim3(2048), dim3(64),  0, stream, q, F, Af);
    hipLaunchKernelGGL((k_gemm_bt<0>), dim3(256), dim3(256), 0, stream, (const void*)Af, Wv, P1);
    hipLaunchKernelGGL(k_cmul,    dim3(512),  dim3(256), 0, stream, P1, bv, wr, wi, Y);
    hipLaunchKernelGGL((k_gemm_bt<1>), dim3(256), dim3(256), 0, stream, (const void*)Y, Wo, P2);
    hipLaunchKernelGGL(k_reduce8, dim3(1024), dim3(256), 0, stream, P2, Zb);
    hipLaunchKernelGGL(k_dft_inv, dim3(1024), dim3(256), 0, stream, G, Zb, bo, out);
}